// Round 1
// baseline (1419.762 us; speedup 1.0000x reference)
//
#include <hip/hip_runtime.h>
#include <math.h>

// Problem constants (match reference)
constexpr int kNodes   = 40000;
constexpr int kEdges   = 640000;
constexpr int kEmb     = 128;
constexpr int kOut     = 256;
constexpr int kTargets = 12;
constexpr int kRadial  = 6;

// ---------------------------------------------------------------------------
// Kernel 1: g = rbf @ W_rbf ; xe = g*x ; atomic scatter-add into pooled[N,128]
// 32 lanes per edge, 4 floats per lane (float4). 8 edges per 256-thread block.
// ---------------------------------------------------------------------------
__global__ __launch_bounds__(256) void edge_scatter_kernel(
    const float* __restrict__ x, const float* __restrict__ rbf,
    const int* __restrict__ idnb, const float* __restrict__ W_rbf,
    float* __restrict__ pooled) {
  __shared__ float wLds[kRadial * kEmb];  // 3 KB
  for (int i = threadIdx.x; i < kRadial * kEmb; i += 256) wLds[i] = W_rbf[i];
  __syncthreads();

  const int tid  = threadIdx.x;
  const int lane = tid & 31;                      // 32 lanes per edge
  const long e   = (long)blockIdx.x * 8 + (tid >> 5);
  if (e >= kEdges) return;

  const float4 xv = *(const float4*)(x + e * kEmb + lane * 4);
  float r[kRadial];
#pragma unroll
  for (int j = 0; j < kRadial; ++j) r[j] = rbf[e * kRadial + j];

  float4 g = make_float4(0.f, 0.f, 0.f, 0.f);
#pragma unroll
  for (int j = 0; j < kRadial; ++j) {
    const float4 w = *(const float4*)(wLds + j * kEmb + lane * 4);
    g.x += r[j] * w.x;
    g.y += r[j] * w.y;
    g.z += r[j] * w.z;
    g.w += r[j] * w.w;
  }

  const int node = idnb[e];
  float* p = pooled + (long)node * kEmb + lane * 4;
  atomicAdd(p + 0, g.x * xv.x);
  atomicAdd(p + 1, g.y * xv.y);
  atomicAdd(p + 2, g.z * xv.z);
  atomicAdd(p + 3, g.w * xv.w);
}

// ---------------------------------------------------------------------------
// Kernel 2..5: C[M,N] = (ACT ? silu(A@B + bias) : A@B)
// f32, BM=BN=64, BK=32, 256 threads (16x16), 4x4 register tile per thread.
// A tile stored transposed in LDS so inner loop reads are contiguous float4.
// ---------------------------------------------------------------------------
template <bool ACT>
__global__ __launch_bounds__(256) void gemm_kernel(
    const float* __restrict__ A, const float* __restrict__ B,
    const float* __restrict__ bias, float* __restrict__ C,
    int M, int K, int N) {
  constexpr int BK = 32;
  __shared__ float As[BK][64];  // [k][m] transposed
  __shared__ float Bs[BK][64];  // [k][n]

  const int tid = threadIdx.x;
  const int tx = tid & 15;       // col group
  const int ty = tid >> 4;       // row group
  const int rowBase = blockIdx.x * 64;
  const int colBase = blockIdx.y * 64;

  float acc[4][4];
#pragma unroll
  for (int i = 0; i < 4; ++i)
#pragma unroll
    for (int j = 0; j < 4; ++j) acc[i][j] = 0.f;

  for (int k0 = 0; k0 < K; k0 += BK) {
    // Load A tile (64 rows x BK cols), store transposed.
#pragma unroll
    for (int p = 0; p < 2; ++p) {
      const int r  = (tid >> 3) + p * 32;
      const int kc = (tid & 7) * 4;
      const float4 a = *(const float4*)(A + (long)(rowBase + r) * K + k0 + kc);
      As[kc + 0][r] = a.x;
      As[kc + 1][r] = a.y;
      As[kc + 2][r] = a.z;
      As[kc + 3][r] = a.w;
    }
    // Load B tile (BK rows x 64 cols), direct.
#pragma unroll
    for (int p = 0; p < 2; ++p) {
      const int kr = (tid >> 4) + p * 16;
      const int nc = (tid & 15) * 4;
      *(float4*)&Bs[kr][nc] = *(const float4*)(B + (long)(k0 + kr) * N + colBase + nc);
    }
    __syncthreads();

#pragma unroll
    for (int k = 0; k < BK; ++k) {
      const float4 a = *(const float4*)&As[k][ty * 4];
      const float4 b = *(const float4*)&Bs[k][tx * 4];
      const float av[4] = {a.x, a.y, a.z, a.w};
      const float bv[4] = {b.x, b.y, b.z, b.w};
#pragma unroll
      for (int i = 0; i < 4; ++i)
#pragma unroll
        for (int j = 0; j < 4; ++j) acc[i][j] += av[i] * bv[j];
    }
    __syncthreads();
  }

#pragma unroll
  for (int i = 0; i < 4; ++i) {
    const long row = rowBase + ty * 4 + i;
#pragma unroll
    for (int j = 0; j < 4; ++j) {
      const int col = colBase + tx * 4 + j;
      float v = acc[i][j];
      if (ACT) {
        v += bias[col];
        v = v / (1.f + __expf(-v));  // silu
      }
      C[row * N + col] = v;
    }
  }
}

// ---------------------------------------------------------------------------
// Kernel 6: out[M,12] = h[M,256] @ W_final[256,12]
// 16 threads per row, shuffle reduction over the 16-lane group.
// ---------------------------------------------------------------------------
__global__ __launch_bounds__(256) void final_proj_kernel(
    const float* __restrict__ h, const float* __restrict__ Wf,
    float* __restrict__ out) {
  __shared__ float wLds[kOut][kTargets + 1];  // pad to cut bank conflicts
  for (int i = threadIdx.x; i < kOut * kTargets; i += 256)
    wLds[i / kTargets][i % kTargets] = Wf[i];
  __syncthreads();

  const int tid  = threadIdx.x;
  const int sub  = tid & 15;   // 16 threads per row
  const int rsub = tid >> 4;   // 16 rows per block
  const int row  = blockIdx.x * 16 + rsub;

  float acc[kTargets];
#pragma unroll
  for (int n = 0; n < kTargets; ++n) acc[n] = 0.f;

  const float* hr = h + (long)row * kOut + sub * 16;
#pragma unroll
  for (int j4 = 0; j4 < 4; ++j4) {
    const float4 hv = *(const float4*)(hr + j4 * 4);
    const float hvv[4] = {hv.x, hv.y, hv.z, hv.w};
#pragma unroll
    for (int q = 0; q < 4; ++q) {
      const int k = sub * 16 + j4 * 4 + q;
#pragma unroll
      for (int n = 0; n < kTargets; ++n) acc[n] += hvv[q] * wLds[k][n];
    }
  }
  // Reduce across the 16 lanes of this row group (they are contiguous lanes).
#pragma unroll
  for (int mask = 8; mask >= 1; mask >>= 1) {
#pragma unroll
    for (int n = 0; n < kTargets; ++n) acc[n] += __shfl_xor(acc[n], mask, 64);
  }
  if (sub == 0) {
#pragma unroll
    for (int n = 0; n < kTargets; ++n) out[(long)row * kTargets + n] = acc[n];
  }
}

// ---------------------------------------------------------------------------
extern "C" void kernel_launch(void* const* d_in, const int* in_sizes, int n_in,
                              void* d_out, int out_size, void* d_ws, size_t ws_size,
                              hipStream_t stream) {
  // Inputs in setup_inputs() order:
  // 0: n_atoms [40000,128] (shape only)
  // 1: x       [640000,128]
  // 2: rbf     [640000,6]
  // 3: idnb_i  [640000] int32
  // 4: W_rbf   [6,128]
  // 5: W_up    [128,256]
  // 6: W_mlp   [3,256,256]
  // 7: b_mlp   [3,256]
  // 8: W_final [256,12]
  const float* x      = (const float*)d_in[1];
  const float* rbf    = (const float*)d_in[2];
  const int*   idnb   = (const int*)d_in[3];
  const float* W_rbf  = (const float*)d_in[4];
  const float* W_up   = (const float*)d_in[5];
  const float* W_mlp  = (const float*)d_in[6];
  const float* b_mlp  = (const float*)d_in[7];
  const float* W_fin  = (const float*)d_in[8];
  float* out = (float*)d_out;

  // Workspace layout (f32): pooled[40000*128] | hA[40000*256] | hB[40000*256]
  float* pooled = (float*)d_ws;
  float* hA = pooled + (size_t)kNodes * kEmb;
  float* hB = hA + (size_t)kNodes * kOut;

  hipMemsetAsync(pooled, 0, (size_t)kNodes * kEmb * sizeof(float), stream);

  // Edge phase: 8 edges per block.
  edge_scatter_kernel<<<kEdges / 8, 256, 0, stream>>>(x, rbf, idnb, W_rbf, pooled);

  // Node phase.
  dim3 gUp(kNodes / 64, kOut / 64);
  gemm_kernel<false><<<gUp, 256, 0, stream>>>(pooled, W_up, nullptr, hA,
                                              kNodes, kEmb, kOut);
  gemm_kernel<true><<<gUp, 256, 0, stream>>>(hA, W_mlp + 0 * kOut * kOut,
                                             b_mlp + 0 * kOut, hB,
                                             kNodes, kOut, kOut);
  gemm_kernel<true><<<gUp, 256, 0, stream>>>(hB, W_mlp + 1 * kOut * kOut,
                                             b_mlp + 1 * kOut, hA,
                                             kNodes, kOut, kOut);
  gemm_kernel<true><<<gUp, 256, 0, stream>>>(hA, W_mlp + 2 * kOut * kOut,
                                             b_mlp + 2 * kOut, hB,
                                             kNodes, kOut, kOut);

  final_proj_kernel<<<kNodes / 16, 256, 0, stream>>>(hB, W_fin, out);
}

// Round 2
// 596.796 us; speedup vs baseline: 2.3790x; 2.3790x over previous
//
#include <hip/hip_runtime.h>
#include <math.h>

// Problem constants (match reference)
constexpr int kNodes   = 40000;
constexpr int kEdges   = 640000;
constexpr int kEmb     = 128;
constexpr int kOut     = 256;
constexpr int kTargets = 12;
constexpr int kRadial  = 6;

// ---------------------------------------------------------------------------
// CSR build: histogram -> scan -> fill. Int atomics only (L2-resident, cheap).
// ---------------------------------------------------------------------------
__global__ __launch_bounds__(256) void hist_kernel(const int* __restrict__ idnb,
                                                   int* __restrict__ counts) {
  const int e = blockIdx.x * 256 + threadIdx.x;
  if (e < kEdges) atomicAdd(&counts[idnb[e]], 1);
}

__global__ __launch_bounds__(1024) void scan_kernel(const int* __restrict__ counts,
                                                    int* __restrict__ offs,
                                                    int* __restrict__ next) {
  __shared__ int part[1024];
  const int t = threadIdx.x;
  constexpr int chunk = (kNodes + 1023) / 1024;  // 40
  const int base = t * chunk;
  int s = 0;
#pragma unroll
  for (int i = 0; i < chunk; ++i) {
    const int idx = base + i;
    if (idx < kNodes) s += counts[idx];
  }
  part[t] = s;
  __syncthreads();
  for (int d = 1; d < 1024; d <<= 1) {
    const int v = (t >= d) ? part[t - d] : 0;
    __syncthreads();
    part[t] += v;
    __syncthreads();
  }
  int excl = (t == 0) ? 0 : part[t - 1];
  for (int i = 0; i < chunk; ++i) {
    const int idx = base + i;
    if (idx < kNodes) {
      offs[idx] = excl;
      next[idx] = excl;
      excl += counts[idx];
    }
  }
  if (t == 0) offs[kNodes] = kEdges;
}

__global__ __launch_bounds__(256) void fill_kernel(const int* __restrict__ idnb,
                                                   int* __restrict__ next,
                                                   int* __restrict__ edgeIdx) {
  const int e = blockIdx.x * 256 + threadIdx.x;
  if (e < kEdges) {
    const int p = atomicAdd(&next[idnb[e]], 1);
    edgeIdx[p] = e;
  }
}

// ---------------------------------------------------------------------------
// Gather: 32 lanes per node, 8 nodes per 256-thread block. Each lane owns 4
// of the 128 dims. Per edge: rbf row (6 scalars), g = rbf @ W_rbf (W in regs),
// acc += g * x[e]. One float4 store per lane at the end. No f32 atomics.
// ---------------------------------------------------------------------------
__global__ __launch_bounds__(256) void gather_kernel(
    const float* __restrict__ x, const float* __restrict__ rbf,
    const int* __restrict__ offs, const int* __restrict__ edgeIdx,
    const float* __restrict__ W_rbf, float* __restrict__ pooled) {
  __shared__ float wLds[kRadial * kEmb];  // 3 KB
  for (int i = threadIdx.x; i < kRadial * kEmb; i += 256) wLds[i] = W_rbf[i];
  __syncthreads();

  const int sub = threadIdx.x & 31;   // lane within node group
  const int n   = blockIdx.x * 8 + (threadIdx.x >> 5);
  if (n >= kNodes) return;

  // Hoist this lane's 4 columns of W_rbf (6 rows) into registers.
  float4 w[kRadial];
#pragma unroll
  for (int j = 0; j < kRadial; ++j)
    w[j] = *(const float4*)(wLds + j * kEmb + sub * 4);

  const int beg = offs[n], end = offs[n + 1];
  float4 acc = make_float4(0.f, 0.f, 0.f, 0.f);

  for (int i = beg; i < end; ++i) {
    const int e = edgeIdx[i];
    const float* rr = rbf + (long)e * kRadial;
    float4 g = make_float4(0.f, 0.f, 0.f, 0.f);
#pragma unroll
    for (int j = 0; j < kRadial; ++j) {
      const float rj = rr[j];
      g.x += rj * w[j].x;
      g.y += rj * w[j].y;
      g.z += rj * w[j].z;
      g.w += rj * w[j].w;
    }
    const float4 xv = *(const float4*)(x + (long)e * kEmb + sub * 4);
    acc.x += g.x * xv.x;
    acc.y += g.y * xv.y;
    acc.z += g.z * xv.z;
    acc.w += g.w * xv.w;
  }
  *(float4*)(pooled + (long)n * kEmb + sub * 4) = acc;
}

// ---------------------------------------------------------------------------
// GEMM: C[M,N] = (ACT ? silu(A@B + bias) : A@B)
// f32, BM=BN=64, BK=32, 256 threads (16x16), 4x4 register tile per thread.
// ---------------------------------------------------------------------------
template <bool ACT>
__global__ __launch_bounds__(256) void gemm_kernel(
    const float* __restrict__ A, const float* __restrict__ B,
    const float* __restrict__ bias, float* __restrict__ C,
    int M, int K, int N) {
  constexpr int BK = 32;
  __shared__ float As[BK][64];  // [k][m] transposed
  __shared__ float Bs[BK][64];  // [k][n]

  const int tid = threadIdx.x;
  const int tx = tid & 15;
  const int ty = tid >> 4;
  const int rowBase = blockIdx.x * 64;
  const int colBase = blockIdx.y * 64;

  float acc[4][4];
#pragma unroll
  for (int i = 0; i < 4; ++i)
#pragma unroll
    for (int j = 0; j < 4; ++j) acc[i][j] = 0.f;

  for (int k0 = 0; k0 < K; k0 += BK) {
#pragma unroll
    for (int p = 0; p < 2; ++p) {
      const int r  = (tid >> 3) + p * 32;
      const int kc = (tid & 7) * 4;
      const float4 a = *(const float4*)(A + (long)(rowBase + r) * K + k0 + kc);
      As[kc + 0][r] = a.x;
      As[kc + 1][r] = a.y;
      As[kc + 2][r] = a.z;
      As[kc + 3][r] = a.w;
    }
#pragma unroll
    for (int p = 0; p < 2; ++p) {
      const int kr = (tid >> 4) + p * 16;
      const int nc = (tid & 15) * 4;
      *(float4*)&Bs[kr][nc] = *(const float4*)(B + (long)(k0 + kr) * N + colBase + nc);
    }
    __syncthreads();

#pragma unroll
    for (int k = 0; k < BK; ++k) {
      const float4 a = *(const float4*)&As[k][ty * 4];
      const float4 b = *(const float4*)&Bs[k][tx * 4];
      const float av[4] = {a.x, a.y, a.z, a.w};
      const float bv[4] = {b.x, b.y, b.z, b.w};
#pragma unroll
      for (int i = 0; i < 4; ++i)
#pragma unroll
        for (int j = 0; j < 4; ++j) acc[i][j] += av[i] * bv[j];
    }
    __syncthreads();
  }

#pragma unroll
  for (int i = 0; i < 4; ++i) {
    const long row = rowBase + ty * 4 + i;
#pragma unroll
    for (int j = 0; j < 4; ++j) {
      const int col = colBase + tx * 4 + j;
      float v = acc[i][j];
      if (ACT) {
        v += bias[col];
        v = v / (1.f + __expf(-v));  // silu
      }
      C[row * N + col] = v;
    }
  }
}

// ---------------------------------------------------------------------------
// Final: out[M,12] = h[M,256] @ W_final[256,12]
// ---------------------------------------------------------------------------
__global__ __launch_bounds__(256) void final_proj_kernel(
    const float* __restrict__ h, const float* __restrict__ Wf,
    float* __restrict__ out) {
  __shared__ float wLds[kOut][kTargets + 1];
  for (int i = threadIdx.x; i < kOut * kTargets; i += 256)
    wLds[i / kTargets][i % kTargets] = Wf[i];
  __syncthreads();

  const int tid  = threadIdx.x;
  const int sub  = tid & 15;
  const int rsub = tid >> 4;
  const int row  = blockIdx.x * 16 + rsub;

  float acc[kTargets];
#pragma unroll
  for (int n = 0; n < kTargets; ++n) acc[n] = 0.f;

  const float* hr = h + (long)row * kOut + sub * 16;
#pragma unroll
  for (int j4 = 0; j4 < 4; ++j4) {
    const float4 hv = *(const float4*)(hr + j4 * 4);
    const float hvv[4] = {hv.x, hv.y, hv.z, hv.w};
#pragma unroll
    for (int q = 0; q < 4; ++q) {
      const int k = sub * 16 + j4 * 4 + q;
#pragma unroll
      for (int n = 0; n < kTargets; ++n) acc[n] += hvv[q] * wLds[k][n];
    }
  }
#pragma unroll
  for (int mask = 8; mask >= 1; mask >>= 1) {
#pragma unroll
    for (int n = 0; n < kTargets; ++n) acc[n] += __shfl_xor(acc[n], mask, 64);
  }
  if (sub == 0) {
#pragma unroll
    for (int n = 0; n < kTargets; ++n) out[(long)row * kTargets + n] = acc[n];
  }
}

// ---------------------------------------------------------------------------
extern "C" void kernel_launch(void* const* d_in, const int* in_sizes, int n_in,
                              void* d_out, int out_size, void* d_ws, size_t ws_size,
                              hipStream_t stream) {
  const float* x      = (const float*)d_in[1];
  const float* rbf    = (const float*)d_in[2];
  const int*   idnb   = (const int*)d_in[3];
  const float* W_rbf  = (const float*)d_in[4];
  const float* W_up   = (const float*)d_in[5];
  const float* W_mlp  = (const float*)d_in[6];
  const float* b_mlp  = (const float*)d_in[7];
  const float* W_fin  = (const float*)d_in[8];
  float* out = (float*)d_out;

  // Workspace layout (f32): pooled[40000*128] | hA[40000*256] | hB[40000*256]
  // CSR arrays alias the hA region: they are dead before hA is first written
  // (single-stream ordering), so no extra workspace is needed.
  float* pooled = (float*)d_ws;
  float* hA = pooled + (size_t)kNodes * kEmb;
  float* hB = hA + (size_t)kNodes * kOut;

  int* counts  = (int*)hA;
  int* offs    = counts + 40960;            // kNodes+1 entries
  int* next    = offs + 40961;
  int* edgeIdx = next + 40960;              // kEdges entries

  hipMemsetAsync(counts, 0, (size_t)kNodes * sizeof(int), stream);

  // CSR build.
  hist_kernel<<<(kEdges + 255) / 256, 256, 0, stream>>>(idnb, counts);
  scan_kernel<<<1, 1024, 0, stream>>>(counts, offs, next);
  fill_kernel<<<(kEdges + 255) / 256, 256, 0, stream>>>(idnb, next, edgeIdx);

  // Edge gather (replaces atomic scatter).
  gather_kernel<<<kNodes / 8, 256, 0, stream>>>(x, rbf, offs, edgeIdx, W_rbf,
                                                pooled);

  // Node phase.
  dim3 gUp(kNodes / 64, kOut / 64);
  gemm_kernel<false><<<gUp, 256, 0, stream>>>(pooled, W_up, nullptr, hA,
                                              kNodes, kEmb, kOut);
  gemm_kernel<true><<<gUp, 256, 0, stream>>>(hA, W_mlp + 0 * kOut * kOut,
                                             b_mlp + 0 * kOut, hB,
                                             kNodes, kOut, kOut);
  gemm_kernel<true><<<gUp, 256, 0, stream>>>(hB, W_mlp + 1 * kOut * kOut,
                                             b_mlp + 1 * kOut, hA,
                                             kNodes, kOut, kOut);
  gemm_kernel<true><<<gUp, 256, 0, stream>>>(hA, W_mlp + 2 * kOut * kOut,
                                             b_mlp + 2 * kOut, hB,
                                             kNodes, kOut, kOut);

  final_proj_kernel<<<kNodes / 16, 256, 0, stream>>>(hB, W_fin, out);
}

// Round 3
// 352.677 us; speedup vs baseline: 4.0257x; 1.6922x over previous
//
#include <hip/hip_runtime.h>
#include <math.h>

constexpr int kNodes   = 40000;
constexpr int kEdges   = 640000;
constexpr int kEmb     = 128;
constexpr int kOut     = 256;
constexpr int kTargets = 12;
constexpr int kRadial  = 6;

typedef float        f32x4 __attribute__((ext_vector_type(4)));
typedef unsigned int u32x4 __attribute__((ext_vector_type(4)));

__device__ __forceinline__ unsigned short f2bf(float f) {
  unsigned int u = __float_as_uint(f);
  u += 0x7fff + ((u >> 16) & 1);          // round-to-nearest-even
  return (unsigned short)(u >> 16);
}
__device__ __forceinline__ float bf2f(unsigned short h) {
  return __uint_as_float(((unsigned int)h) << 16);
}
__device__ __forceinline__ void mfma16(f32x4& c, u32x4 a, u32x4 b) {
  asm volatile("v_mfma_f32_16x16x32_bf16 %0, %1, %2, %0" : "+v"(c) : "v"(a), "v"(b));
}

// ---------------------------------------------------------------------------
// CSR build (all multi-block, coalesced; int atomics only)
// ---------------------------------------------------------------------------
__global__ __launch_bounds__(256) void zero_counts(int* __restrict__ c) {
  const int i = blockIdx.x * 256 + threadIdx.x;
  if (i < kNodes) c[i] = 0;
}

__global__ __launch_bounds__(256) void hist_kernel(const int* __restrict__ idnb,
                                                   int* __restrict__ counts) {
  const int e = blockIdx.x * 256 + threadIdx.x;
  if (e < kEdges) atomicAdd(&counts[idnb[e]], 1);
}

__global__ __launch_bounds__(256) void scan_pass1(const int* __restrict__ counts,
                                                  int* __restrict__ bsum) {
  __shared__ int sm[256];
  const int idx = blockIdx.x * 256 + threadIdx.x;
  sm[threadIdx.x] = (idx < kNodes) ? counts[idx] : 0;
  __syncthreads();
  for (int d = 128; d > 0; d >>= 1) {
    if (threadIdx.x < d) sm[threadIdx.x] += sm[threadIdx.x + d];
    __syncthreads();
  }
  if (threadIdx.x == 0) bsum[blockIdx.x] = sm[0];
}

__global__ __launch_bounds__(256) void scan_pass2(const int* __restrict__ bsum,
                                                  int* __restrict__ bscan,
                                                  int* __restrict__ offs,
                                                  int nblk) {
  __shared__ int sm[256];
  const int t = threadIdx.x;
  const int v = (t < nblk) ? bsum[t] : 0;
  sm[t] = v;
  __syncthreads();
  for (int d = 1; d < 256; d <<= 1) {
    const int x = (t >= d) ? sm[t - d] : 0;
    __syncthreads();
    sm[t] += x;
    __syncthreads();
  }
  if (t < nblk) bscan[t] = sm[t] - v;   // exclusive
  if (t == 0) offs[kNodes] = kEdges;
}

__global__ __launch_bounds__(256) void scan_pass3(const int* __restrict__ counts,
                                                  const int* __restrict__ bscan,
                                                  int* __restrict__ offs,
                                                  int* __restrict__ next) {
  __shared__ int sm[256];
  const int t = threadIdx.x;
  const int idx = blockIdx.x * 256 + t;
  const int v = (idx < kNodes) ? counts[idx] : 0;
  sm[t] = v;
  __syncthreads();
  for (int d = 1; d < 256; d <<= 1) {
    const int x = (t >= d) ? sm[t - d] : 0;
    __syncthreads();
    sm[t] += x;
    __syncthreads();
  }
  if (idx < kNodes) {
    const int e = bscan[blockIdx.x] + sm[t] - v;
    offs[idx] = e;
    next[idx] = e;
  }
}

__global__ __launch_bounds__(256) void fill_kernel(const int* __restrict__ idnb,
                                                   int* __restrict__ next,
                                                   int* __restrict__ edgeIdx) {
  const int e = blockIdx.x * 256 + threadIdx.x;
  if (e < kEdges) {
    const int p = atomicAdd(&next[idnb[e]], 1);
    edgeIdx[p] = e;
  }
}

// ---------------------------------------------------------------------------
// Weight prep: split f32 -> (hi,lo) bf16 and transpose to [N][K] row-major.
// ---------------------------------------------------------------------------
__global__ __launch_bounds__(256) void prep_weights(
    const float* __restrict__ Wup, const float* __restrict__ Wmlp,
    unsigned short* __restrict__ WtUpHi, unsigned short* __restrict__ WtUpLo,
    unsigned short* __restrict__ WtMHi, unsigned short* __restrict__ WtMLo) {
  const int id = blockIdx.x * 256 + threadIdx.x;
  if (id < 256 * 128) {                       // W_up^T [256][128]
    const int n = id >> 7, k = id & 127;
    const float v = Wup[k * 256 + n];
    const unsigned short h = f2bf(v);
    WtUpHi[id] = h;
    WtUpLo[id] = f2bf(v - bf2f(h));
  }
  const int id2 = id - 256 * 128;
  if (id2 >= 0 && id2 < 3 * 256 * 256) {      // W_mlp^T [3][256][256]
    const int l = id2 >> 16, rem = id2 & 65535, n = rem >> 8, k = rem & 255;
    const float v = Wmlp[l * 65536 + k * 256 + n];
    const unsigned short h = f2bf(v);
    WtMHi[id2] = h;
    WtMLo[id2] = f2bf(v - bf2f(h));
  }
}

// ---------------------------------------------------------------------------
// Gather: 32 lanes per node, outputs pooled as (hi,lo) bf16 pairs.
// ---------------------------------------------------------------------------
__global__ __launch_bounds__(256) void gather_kernel(
    const float* __restrict__ x, const float* __restrict__ rbf,
    const int* __restrict__ offs, const int* __restrict__ edgeIdx,
    const float* __restrict__ W_rbf,
    unsigned short* __restrict__ pHi, unsigned short* __restrict__ pLo) {
  __shared__ float wLds[kRadial * kEmb];
  for (int i = threadIdx.x; i < kRadial * kEmb; i += 256) wLds[i] = W_rbf[i];
  __syncthreads();

  const int sub = threadIdx.x & 31;
  const int n   = blockIdx.x * 8 + (threadIdx.x >> 5);

  float4 w[kRadial];
#pragma unroll
  for (int j = 0; j < kRadial; ++j)
    w[j] = *(const float4*)(wLds + j * kEmb + sub * 4);

  const int beg = offs[n], end = offs[n + 1];
  float4 acc = make_float4(0.f, 0.f, 0.f, 0.f);

  for (int i = beg; i < end; ++i) {
    const int e = edgeIdx[i];
    const float* rr = rbf + (long)e * kRadial;
    float4 g = make_float4(0.f, 0.f, 0.f, 0.f);
#pragma unroll
    for (int j = 0; j < kRadial; ++j) {
      const float rj = rr[j];
      g.x += rj * w[j].x;
      g.y += rj * w[j].y;
      g.z += rj * w[j].z;
      g.w += rj * w[j].w;
    }
    const float4 xv = *(const float4*)(x + (long)e * kEmb + sub * 4);
    acc.x += g.x * xv.x;
    acc.y += g.y * xv.y;
    acc.z += g.z * xv.z;
    acc.w += g.w * xv.w;
  }
  const float av[4] = {acc.x, acc.y, acc.z, acc.w};
  ushort4 hv, lv;
  unsigned short* hp = (unsigned short*)&hv;
  unsigned short* lp = (unsigned short*)&lv;
#pragma unroll
  for (int q = 0; q < 4; ++q) {
    const unsigned short h = f2bf(av[q]);
    hp[q] = h;
    lp[q] = f2bf(av[q] - bf2f(h));
  }
  *(ushort4*)(pHi + (size_t)n * kEmb + sub * 4) = hv;
  *(ushort4*)(pLo + (size_t)n * kEmb + sub * 4) = lv;
}

// ---------------------------------------------------------------------------
// bf16x3 split MFMA GEMM.  C[M=40000 (625x64), N=256] = A[M,K] @ B[K,256].
// A given as (hi,lo) bf16 [M][K]; B given transposed (hi,lo) bf16 [256][K].
// 256 thr = 4 waves; wave w owns cols w*64..w*64+63 (4x4 fragments of 16x16).
// ---------------------------------------------------------------------------
template <int K, bool ACT, bool SPLIT>
__global__ __launch_bounds__(256) void gemm_mfma(
    const unsigned short* __restrict__ Ahi, const unsigned short* __restrict__ Alo,
    const unsigned short* __restrict__ Bhi, const unsigned short* __restrict__ Blo,
    const float* __restrict__ bias,
    unsigned short* __restrict__ Chi, unsigned short* __restrict__ Clo,
    float* __restrict__ Cf) {
  __shared__ unsigned short sAh[64][40], sAl[64][40];   // padded rows: 80 B
  __shared__ unsigned short sBh[256][40], sBl[256][40];

  const int tid     = threadIdx.x;
  const int rowBase = blockIdx.x * 64;
  const int w    = tid >> 6;
  const int lane = tid & 63;
  const int lrow = lane & 15;
  const int kgrp = lane >> 4;

  f32x4 acc[4][4];
#pragma unroll
  for (int i = 0; i < 4; ++i)
#pragma unroll
    for (int j = 0; j < 4; ++j) acc[i][j] = f32x4{0.f, 0.f, 0.f, 0.f};

  const int ar = tid >> 2, ac = tid & 3;

  for (int k0 = 0; k0 < K; k0 += 32) {
    {  // stage A tile (64 x 32), hi + lo
      const size_t g = (size_t)(rowBase + ar) * K + k0 + ac * 8;
      const u32x4 vh = *(const u32x4*)(Ahi + g);
      const u32x4 vl = *(const u32x4*)(Alo + g);
      *(u32x4*)(&sAh[ar][ac * 8]) = vh;
      *(u32x4*)(&sAl[ar][ac * 8]) = vl;
    }
#pragma unroll
    for (int p = 0; p < 4; ++p) {  // stage B^T tile (256 x 32), hi + lo
      const int chunk = p * 256 + tid;
      const int n = chunk >> 2, c = chunk & 3;
      const size_t g = (size_t)n * K + k0 + c * 8;
      const u32x4 vh = *(const u32x4*)(Bhi + g);
      const u32x4 vl = *(const u32x4*)(Blo + g);
      *(u32x4*)(&sBh[n][c * 8]) = vh;
      *(u32x4*)(&sBl[n][c * 8]) = vl;
    }
    __syncthreads();

    u32x4 ah[4], al[4];
#pragma unroll
    for (int i = 0; i < 4; ++i) {
      ah[i] = *(const u32x4*)(&sAh[i * 16 + lrow][kgrp * 8]);
      al[i] = *(const u32x4*)(&sAl[i * 16 + lrow][kgrp * 8]);
    }
#pragma unroll
    for (int j = 0; j < 4; ++j) {
      const int bn = w * 64 + j * 16 + lrow;
      const u32x4 bh = *(const u32x4*)(&sBh[bn][kgrp * 8]);
      const u32x4 bl = *(const u32x4*)(&sBl[bn][kgrp * 8]);
#pragma unroll
      for (int i = 0; i < 4; ++i) {
        mfma16(acc[i][j], ah[i], bh);
        mfma16(acc[i][j], al[i], bh);
        mfma16(acc[i][j], ah[i], bl);
      }
    }
    __syncthreads();
  }

  // Epilogue: C row = (lane>>4)*4 + r, col = lane&15 (m89-verified layout).
#pragma unroll
  for (int j = 0; j < 4; ++j) {
    const int col = w * 64 + j * 16 + lrow;
    const float bj = ACT ? bias[col] : 0.f;
#pragma unroll
    for (int i = 0; i < 4; ++i) {
#pragma unroll
      for (int r = 0; r < 4; ++r) {
        float v = acc[i][j][r];
        if (ACT) {
          v += bj;
          v = v / (1.f + __expf(-v));   // silu
        }
        const size_t o = (size_t)(rowBase + i * 16 + kgrp * 4 + r) * 256 + col;
        if (SPLIT) {
          const unsigned short h = f2bf(v);
          Chi[o] = h;
          Clo[o] = f2bf(v - bf2f(h));
        } else {
          Cf[o] = v;
        }
      }
    }
  }
}

// ---------------------------------------------------------------------------
// Final: out[M,12] = h[M,256] @ W_final[256,12]   (f32)
// ---------------------------------------------------------------------------
__global__ __launch_bounds__(256) void final_proj_kernel(
    const float* __restrict__ h, const float* __restrict__ Wf,
    float* __restrict__ out) {
  __shared__ float wLds[kOut][kTargets + 1];
  for (int i = threadIdx.x; i < kOut * kTargets; i += 256)
    wLds[i / kTargets][i % kTargets] = Wf[i];
  __syncthreads();

  const int tid  = threadIdx.x;
  const int sub  = tid & 15;
  const int rsub = tid >> 4;
  const int row  = blockIdx.x * 16 + rsub;

  float acc[kTargets];
#pragma unroll
  for (int n = 0; n < kTargets; ++n) acc[n] = 0.f;

  const float* hr = h + (size_t)row * kOut + sub * 16;
#pragma unroll
  for (int j4 = 0; j4 < 4; ++j4) {
    const float4 hv = *(const float4*)(hr + j4 * 4);
    const float hvv[4] = {hv.x, hv.y, hv.z, hv.w};
#pragma unroll
    for (int q = 0; q < 4; ++q) {
      const int k = sub * 16 + j4 * 4 + q;
#pragma unroll
      for (int n = 0; n < kTargets; ++n) acc[n] += hvv[q] * wLds[k][n];
    }
  }
#pragma unroll
  for (int mask = 8; mask >= 1; mask >>= 1) {
#pragma unroll
    for (int n = 0; n < kTargets; ++n) acc[n] += __shfl_xor(acc[n], mask, 64);
  }
  if (sub == 0) {
#pragma unroll
    for (int n = 0; n < kTargets; ++n) out[(size_t)row * kTargets + n] = acc[n];
  }
}

// ---------------------------------------------------------------------------
extern "C" void kernel_launch(void* const* d_in, const int* in_sizes, int n_in,
                              void* d_out, int out_size, void* d_ws, size_t ws_size,
                              hipStream_t stream) {
  const float* x      = (const float*)d_in[1];
  const float* rbf    = (const float*)d_in[2];
  const int*   idnb   = (const int*)d_in[3];
  const float* W_rbf  = (const float*)d_in[4];
  const float* W_up   = (const float*)d_in[5];
  const float* W_mlp  = (const float*)d_in[6];
  const float* b_mlp  = (const float*)d_in[7];
  const float* W_fin  = (const float*)d_in[8];
  float* out = (float*)d_out;

  // Workspace carve-up (256 B aligned regions).
  char* wp = (char*)d_ws;
  auto alloc = [&](size_t bytes) -> void* {
    void* r = wp;
    wp += (bytes + 255) & ~(size_t)255;
    return r;
  };
  unsigned short* pHi   = (unsigned short*)alloc((size_t)kNodes * kEmb * 2);
  unsigned short* pLo   = (unsigned short*)alloc((size_t)kNodes * kEmb * 2);
  unsigned short* hAhi  = (unsigned short*)alloc((size_t)kNodes * kOut * 2);
  unsigned short* hAlo  = (unsigned short*)alloc((size_t)kNodes * kOut * 2);
  unsigned short* hBhi  = (unsigned short*)alloc((size_t)kNodes * kOut * 2);
  unsigned short* hBlo  = (unsigned short*)alloc((size_t)kNodes * kOut * 2);
  float* hf = (float*)hBhi;  // aliases hB (dead when G4 writes; G4 reads hA)
  unsigned short* WtUpHi = (unsigned short*)alloc(256 * 128 * 2);
  unsigned short* WtUpLo = (unsigned short*)alloc(256 * 128 * 2);
  unsigned short* WtMHi  = (unsigned short*)alloc(3 * 256 * 256 * 2);
  unsigned short* WtMLo  = (unsigned short*)alloc(3 * 256 * 256 * 2);
  int* counts  = (int*)alloc((size_t)kNodes * 4);
  int* offs    = (int*)alloc((size_t)(kNodes + 8) * 4);
  int* next    = (int*)alloc((size_t)kNodes * 4);
  int* edgeIdx = (int*)alloc((size_t)kEdges * 4);
  int* bsum    = (int*)alloc(256 * 4);
  int* bscan   = (int*)alloc(256 * 4);

  constexpr int nScanBlk = (kNodes + 255) / 256;  // 157

  // CSR build.
  zero_counts<<<nScanBlk, 256, 0, stream>>>(counts);
  hist_kernel<<<kEdges / 256, 256, 0, stream>>>(idnb, counts);
  scan_pass1<<<nScanBlk, 256, 0, stream>>>(counts, bsum);
  scan_pass2<<<1, 256, 0, stream>>>(bsum, bscan, offs, nScanBlk);
  scan_pass3<<<nScanBlk, 256, 0, stream>>>(counts, bscan, offs, next);
  fill_kernel<<<kEdges / 256, 256, 0, stream>>>(idnb, next, edgeIdx);

  // Weight split/transpose (independent).
  prep_weights<<<(256 * 128 + 3 * 256 * 256) / 256, 256, 0, stream>>>(
      W_up, W_mlp, WtUpHi, WtUpLo, WtMHi, WtMLo);

  // Edge gather -> pooled (hi/lo bf16).
  gather_kernel<<<kNodes / 8, 256, 0, stream>>>(x, rbf, offs, edgeIdx, W_rbf,
                                                pHi, pLo);

  // Node MLP via bf16x3 MFMA.
  gemm_mfma<128, false, true><<<kNodes / 64, 256, 0, stream>>>(
      pHi, pLo, WtUpHi, WtUpLo, nullptr, hAhi, hAlo, nullptr);
  gemm_mfma<256, true, true><<<kNodes / 64, 256, 0, stream>>>(
      hAhi, hAlo, WtMHi + 0 * 65536, WtMLo + 0 * 65536, b_mlp + 0 * kOut,
      hBhi, hBlo, nullptr);
  gemm_mfma<256, true, true><<<kNodes / 64, 256, 0, stream>>>(
      hBhi, hBlo, WtMHi + 1 * 65536, WtMLo + 1 * 65536, b_mlp + 1 * kOut,
      hAhi, hAlo, nullptr);
  gemm_mfma<256, true, false><<<kNodes / 64, 256, 0, stream>>>(
      hAhi, hAlo, WtMHi + 2 * 65536, WtMLo + 2 * 65536, b_mlp + 2 * kOut,
      nullptr, nullptr, hf);

  final_proj_kernel<<<kNodes / 16, 256, 0, stream>>>(hf, W_fin, out);
}

// Round 4
// 241.473 us; speedup vs baseline: 5.8796x; 1.4605x over previous
//
#include <hip/hip_runtime.h>
#include <hip/hip_fp16.h>
#include <math.h>

constexpr int kNodes   = 40000;
constexpr int kEdges   = 640000;
constexpr int kEmb     = 128;
constexpr int kOut     = 256;
constexpr int kTargets = 12;
constexpr int kRadial  = 6;

typedef float        f32x4 __attribute__((ext_vector_type(4)));
typedef unsigned int u32x4 __attribute__((ext_vector_type(4)));

__device__ __forceinline__ unsigned short f2h(float f) {
  return __half_as_ushort(__float2half(f));   // RTNE
}
__device__ __forceinline__ void mfma_f16(f32x4& c, u32x4 a, u32x4 b) {
  asm volatile("v_mfma_f32_16x16x32_f16 %0, %1, %2, %0" : "+v"(c) : "v"(a), "v"(b));
}

// ---------------------------------------------------------------------------
// CSR build (multi-block, coalesced; int atomics only)
// ---------------------------------------------------------------------------
__global__ __launch_bounds__(256) void zero_counts(int* __restrict__ c) {
  const int i = blockIdx.x * 256 + threadIdx.x;
  if (i < kNodes) c[i] = 0;
}

__global__ __launch_bounds__(256) void hist_kernel(const int* __restrict__ idnb,
                                                   int* __restrict__ counts) {
  const int e = blockIdx.x * 256 + threadIdx.x;
  if (e < kEdges) atomicAdd(&counts[idnb[e]], 1);
}

__global__ __launch_bounds__(256) void scan_pass1(const int* __restrict__ counts,
                                                  int* __restrict__ bsum) {
  __shared__ int sm[256];
  const int idx = blockIdx.x * 256 + threadIdx.x;
  sm[threadIdx.x] = (idx < kNodes) ? counts[idx] : 0;
  __syncthreads();
  for (int d = 128; d > 0; d >>= 1) {
    if (threadIdx.x < d) sm[threadIdx.x] += sm[threadIdx.x + d];
    __syncthreads();
  }
  if (threadIdx.x == 0) bsum[blockIdx.x] = sm[0];
}

__global__ __launch_bounds__(256) void scan_pass2(const int* __restrict__ bsum,
                                                  int* __restrict__ bscan,
                                                  int* __restrict__ offs,
                                                  int nblk) {
  __shared__ int sm[256];
  const int t = threadIdx.x;
  const int v = (t < nblk) ? bsum[t] : 0;
  sm[t] = v;
  __syncthreads();
  for (int d = 1; d < 256; d <<= 1) {
    const int x = (t >= d) ? sm[t - d] : 0;
    __syncthreads();
    sm[t] += x;
    __syncthreads();
  }
  if (t < nblk) bscan[t] = sm[t] - v;   // exclusive
  if (t == 0) offs[kNodes] = kEdges;
}

__global__ __launch_bounds__(256) void scan_pass3(const int* __restrict__ counts,
                                                  const int* __restrict__ bscan,
                                                  int* __restrict__ offs,
                                                  int* __restrict__ next) {
  __shared__ int sm[256];
  const int t = threadIdx.x;
  const int idx = blockIdx.x * 256 + t;
  const int v = (idx < kNodes) ? counts[idx] : 0;
  sm[t] = v;
  __syncthreads();
  for (int d = 1; d < 256; d <<= 1) {
    const int x = (t >= d) ? sm[t - d] : 0;
    __syncthreads();
    sm[t] += x;
    __syncthreads();
  }
  if (idx < kNodes) {
    const int e = bscan[blockIdx.x] + sm[t] - v;
    offs[idx] = e;
    next[idx] = e;
  }
}

__global__ __launch_bounds__(256) void fill_kernel(const int* __restrict__ idnb,
                                                   int* __restrict__ next,
                                                   int* __restrict__ edgeIdx) {
  const int e = blockIdx.x * 256 + threadIdx.x;
  if (e < kEdges) {
    const int p = atomicAdd(&next[idnb[e]], 1);
    edgeIdx[p] = e;
  }
}

// ---------------------------------------------------------------------------
// Weight prep: f32 -> fp16, transposed to [N][K] row-major.
//   WtUp  [256][128], WtM [3][256][256], WtFin [16][256] (targets padded 12->16)
// ---------------------------------------------------------------------------
__global__ __launch_bounds__(256) void prep_weights(
    const float* __restrict__ Wup, const float* __restrict__ Wmlp,
    const float* __restrict__ Wfin,
    unsigned short* __restrict__ WtUp, unsigned short* __restrict__ WtM,
    unsigned short* __restrict__ WtFin) {
  const int id = blockIdx.x * 256 + threadIdx.x;
  if (id < 256 * 128) {
    const int n = id >> 7, k = id & 127;
    WtUp[id] = f2h(Wup[k * 256 + n]);
    return;
  }
  const int id2 = id - 256 * 128;
  if (id2 < 3 * 256 * 256) {
    const int l = id2 >> 16, rem = id2 & 65535, n = rem >> 8, k = rem & 255;
    WtM[id2] = f2h(Wmlp[l * 65536 + k * 256 + n]);
    return;
  }
  const int id3 = id2 - 3 * 256 * 256;
  if (id3 < 16 * 256) {
    const int n = id3 >> 8, k = id3 & 255;
    WtFin[id3] = (n < kTargets) ? f2h(Wfin[k * kTargets + n]) : (unsigned short)0;
  }
}

// ---------------------------------------------------------------------------
// Gather: 32 lanes per node; pooled written as fp16 [kNodes][128].
// ---------------------------------------------------------------------------
__global__ __launch_bounds__(256) void gather_kernel(
    const float* __restrict__ x, const float* __restrict__ rbf,
    const int* __restrict__ offs, const int* __restrict__ edgeIdx,
    const float* __restrict__ W_rbf, unsigned short* __restrict__ pooled) {
  __shared__ float wLds[kRadial * kEmb];
  for (int i = threadIdx.x; i < kRadial * kEmb; i += 256) wLds[i] = W_rbf[i];
  __syncthreads();

  const int sub = threadIdx.x & 31;
  const int n   = blockIdx.x * 8 + (threadIdx.x >> 5);

  float4 w[kRadial];
#pragma unroll
  for (int j = 0; j < kRadial; ++j)
    w[j] = *(const float4*)(wLds + j * kEmb + sub * 4);

  const int beg = offs[n], end = offs[n + 1];
  float4 acc = make_float4(0.f, 0.f, 0.f, 0.f);

  for (int i = beg; i < end; ++i) {
    const int e = edgeIdx[i];
    const float* rr = rbf + (long)e * kRadial;
    float4 g = make_float4(0.f, 0.f, 0.f, 0.f);
#pragma unroll
    for (int j = 0; j < kRadial; ++j) {
      const float rj = rr[j];
      g.x += rj * w[j].x;
      g.y += rj * w[j].y;
      g.z += rj * w[j].z;
      g.w += rj * w[j].w;
    }
    const float4 xv = *(const float4*)(x + (long)e * kEmb + sub * 4);
    acc.x += g.x * xv.x;
    acc.y += g.y * xv.y;
    acc.z += g.z * xv.z;
    acc.w += g.w * xv.w;
  }
  ushort4 hv;
  hv.x = f2h(acc.x);
  hv.y = f2h(acc.y);
  hv.z = f2h(acc.z);
  hv.w = f2h(acc.w);
  *(ushort4*)(pooled + (size_t)n * kEmb + sub * 4) = hv;
}

// ---------------------------------------------------------------------------
// Fused node MLP: 64 rows/block, 625 blocks, 256 thr (4 waves, col-split).
//   layer 0: pooled[64,128] @ WtUp^T      (no bias/act)
//   layer 1-3: h @ WtM[l]^T + b, silu
//   final: h[64,256] @ WtFin^T -> out[64,12]   (k-split across waves + reduce)
// Activations live in LDS (fp16); weights double-buffer-staged per 32-k chunk.
// LDS: act 34.0 KB + sB 41.0 KB = 75 KB -> 2 blocks/CU.
// ---------------------------------------------------------------------------
__global__ __launch_bounds__(256) void fused_mlp(
    const unsigned short* __restrict__ pooled,
    const unsigned short* __restrict__ WtUp,
    const unsigned short* __restrict__ WtM,
    const unsigned short* __restrict__ WtFin,
    const float* __restrict__ b_mlp, float* __restrict__ out) {
  __shared__ unsigned short act[64][266];     // pitch 266: row stride 133 banks (odd)
  __shared__ unsigned short sB[2][256][40];   // padded rows -> ~2-way on frag reads

  const int tid     = threadIdx.x;
  const int rowBase = blockIdx.x * 64;
  const int w    = tid >> 6;
  const int lane = tid & 63;
  const int lrow = lane & 15;
  const int kgrp = lane >> 4;

  // Stage pooled -> act (64 x 128 fp16).
#pragma unroll
  for (int p = 0; p < 4; ++p) {
    const int q = p * 256 + tid;
    const int r = q >> 4, c = q & 15;
    *(u32x4*)&act[r][c * 8] =
        *(const u32x4*)(pooled + (size_t)(rowBase + r) * kEmb + c * 8);
  }
  __syncthreads();

  for (int l = 0; l < 4; ++l) {
    const int K = (l == 0) ? 128 : 256;
    const int nc = K >> 5;
    const unsigned short* W = (l == 0) ? WtUp : WtM + (size_t)(l - 1) * 65536;

    // Prologue: stage chunk 0 -> buf 0.
#pragma unroll
    for (int p = 0; p < 4; ++p) {
      const int q = p * 256 + tid;
      const int n = q >> 2, c4 = q & 3;
      *(u32x4*)&sB[0][n][c4 * 8] = *(const u32x4*)(W + (size_t)n * K + c4 * 8);
    }
    __syncthreads();

    f32x4 acc[4][4];
#pragma unroll
    for (int i = 0; i < 4; ++i)
#pragma unroll
      for (int j = 0; j < 4; ++j) acc[i][j] = f32x4{0.f, 0.f, 0.f, 0.f};

    for (int c = 0; c < nc; ++c) {
      if (c + 1 < nc) {  // stage next chunk into the other buffer
        const int kb = (c + 1) * 32;
#pragma unroll
        for (int p = 0; p < 4; ++p) {
          const int q = p * 256 + tid;
          const int n = q >> 2, c4 = q & 3;
          *(u32x4*)&sB[(c + 1) & 1][n][c4 * 8] =
              *(const u32x4*)(W + (size_t)n * K + kb + c4 * 8);
        }
      }
      u32x4 a[4];
#pragma unroll
      for (int i = 0; i < 4; ++i)
        a[i] = *(const u32x4*)&act[i * 16 + lrow][c * 32 + kgrp * 8];
#pragma unroll
      for (int j = 0; j < 4; ++j) {
        const u32x4 b = *(const u32x4*)&sB[c & 1][w * 64 + j * 16 + lrow][kgrp * 8];
#pragma unroll
        for (int i = 0; i < 4; ++i) mfma_f16(acc[i][j], a[i], b);
      }
      __syncthreads();
    }

    // Epilogue: (act reads all done at last barrier) bias+silu, write act fp16.
    const float* bias = (l >= 1) ? b_mlp + (size_t)(l - 1) * kOut : nullptr;
#pragma unroll
    for (int j = 0; j < 4; ++j) {
      const int col = w * 64 + j * 16 + lrow;
      const float bj = (l >= 1) ? bias[col] : 0.f;
#pragma unroll
      for (int i = 0; i < 4; ++i) {
#pragma unroll
        for (int r = 0; r < 4; ++r) {
          float v = acc[i][j][r];
          if (l >= 1) {
            v += bj;
            v = v / (1.f + __expf(-v));   // silu
          }
          act[i * 16 + kgrp * 4 + r][col] = f2h(v);
        }
      }
    }
    __syncthreads();
  }

  // Final projection: act[64,256] @ WtFin^T[16,256]; wave w covers k=w*64..+63.
  unsigned short (*sWf)[266] = (unsigned short(*)[266]) & sB[0][0][0];  // 8.5 KB
  float (*sPart)[64][17]     = (float(*)[64][17]) & sB[1][0][0];        // 17.4 KB
#pragma unroll
  for (int p = 0; p < 2; ++p) {
    const int q = p * 256 + tid;
    const int n = q >> 5, c = q & 31;
    *(u32x4*)&sWf[n][c * 8] = *(const u32x4*)(WtFin + (size_t)n * 256 + c * 8);
  }
  __syncthreads();

  f32x4 accF[4];
#pragma unroll
  for (int i = 0; i < 4; ++i) accF[i] = f32x4{0.f, 0.f, 0.f, 0.f};
#pragma unroll
  for (int s = 0; s < 2; ++s) {
    const int cc = w * 2 + s;
    const u32x4 b = *(const u32x4*)&sWf[lrow][cc * 32 + kgrp * 8];
#pragma unroll
    for (int i = 0; i < 4; ++i) {
      const u32x4 a = *(const u32x4*)&act[i * 16 + lrow][cc * 32 + kgrp * 8];
      mfma_f16(accF[i], a, b);
    }
  }
#pragma unroll
  for (int i = 0; i < 4; ++i)
#pragma unroll
    for (int r = 0; r < 4; ++r)
      sPart[w][i * 16 + kgrp * 4 + r][lrow] = accF[i][r];
  __syncthreads();

  for (int q = tid; q < 64 * kTargets; q += 256) {
    const int r = q / kTargets, t = q % kTargets;
    out[(size_t)(rowBase + r) * kTargets + t] =
        sPart[0][r][t] + sPart[1][r][t] + sPart[2][r][t] + sPart[3][r][t];
  }
}

// ---------------------------------------------------------------------------
extern "C" void kernel_launch(void* const* d_in, const int* in_sizes, int n_in,
                              void* d_out, int out_size, void* d_ws, size_t ws_size,
                              hipStream_t stream) {
  const float* x      = (const float*)d_in[1];
  const float* rbf    = (const float*)d_in[2];
  const int*   idnb   = (const int*)d_in[3];
  const float* W_rbf  = (const float*)d_in[4];
  const float* W_up   = (const float*)d_in[5];
  const float* W_mlp  = (const float*)d_in[6];
  const float* b_mlp  = (const float*)d_in[7];
  const float* W_fin  = (const float*)d_in[8];
  float* out = (float*)d_out;

  char* wp = (char*)d_ws;
  auto alloc = [&](size_t bytes) -> void* {
    void* r = wp;
    wp += (bytes + 255) & ~(size_t)255;
    return r;
  };
  unsigned short* pooled = (unsigned short*)alloc((size_t)kNodes * kEmb * 2);
  unsigned short* WtUp   = (unsigned short*)alloc(256 * 128 * 2);
  unsigned short* WtM    = (unsigned short*)alloc(3 * 256 * 256 * 2);
  unsigned short* WtFin  = (unsigned short*)alloc(16 * 256 * 2);
  int* counts  = (int*)alloc((size_t)kNodes * 4);
  int* offs    = (int*)alloc((size_t)(kNodes + 8) * 4);
  int* next    = (int*)alloc((size_t)kNodes * 4);
  int* edgeIdx = (int*)alloc((size_t)kEdges * 4);
  int* bsum    = (int*)alloc(256 * 4);
  int* bscan   = (int*)alloc(256 * 4);

  constexpr int nScanBlk = (kNodes + 255) / 256;  // 157

  // CSR build.
  zero_counts<<<nScanBlk, 256, 0, stream>>>(counts);
  hist_kernel<<<kEdges / 256, 256, 0, stream>>>(idnb, counts);
  scan_pass1<<<nScanBlk, 256, 0, stream>>>(counts, bsum);
  scan_pass2<<<1, 256, 0, stream>>>(bsum, bscan, offs, nScanBlk);
  scan_pass3<<<nScanBlk, 256, 0, stream>>>(counts, bscan, offs, next);
  fill_kernel<<<kEdges / 256, 256, 0, stream>>>(idnb, next, edgeIdx);

  // Weight prep (independent of CSR).
  constexpr int prepElems = 256 * 128 + 3 * 256 * 256 + 16 * 256;
  prep_weights<<<(prepElems + 255) / 256, 256, 0, stream>>>(
      W_up, W_mlp, W_fin, WtUp, WtM, WtFin);

  // Edge gather -> pooled fp16.
  gather_kernel<<<kNodes / 8, 256, 0, stream>>>(x, rbf, offs, edgeIdx, W_rbf,
                                                pooled);

  // Fused node MLP + final projection.
  fused_mlp<<<kNodes / 64, 256, 0, stream>>>(pooled, WtUp, WtM, WtFin, b_mlp,
                                             out);
}